// Round 1
// baseline (270.080 us; speedup 1.0000x reference)
//
#include <hip/hip_runtime.h>

typedef __attribute__((ext_vector_type(4))) float f32x4;
typedef __attribute__((ext_vector_type(8))) short s16x8;
typedef __attribute__((ext_vector_type(8))) unsigned short u16x8;

#define T_LEN 2048
#define ENC_D 1024
#define ATT_D 512
#define CONV_C 10

static __device__ __forceinline__ unsigned short f2bf(float f) {
  unsigned int u = __float_as_uint(f);
  u += 0x7FFFu + ((u >> 16) & 1u);
  return (unsigned short)(u >> 16);
}

// ---------------- K0a: Wt[a][k] = bf16(W_enc[k][a]) ----------------
__global__ void k_wt(const float* __restrict__ W, unsigned short* __restrict__ Wt) {
  __shared__ float tile[64][65];
  int k0 = blockIdx.x * 64, a0 = blockIdx.y * 64;
  int tid = threadIdx.x;
  int r = tid >> 2, cg = tid & 3;
  #pragma unroll
  for (int i = 0; i < 4; ++i) {
    f32x4 v = *reinterpret_cast<const f32x4*>(&W[(size_t)(k0 + r) * ATT_D + a0 + cg * 16 + i * 4]);
    tile[r][cg * 16 + i * 4 + 0] = v[0];
    tile[r][cg * 16 + i * 4 + 1] = v[1];
    tile[r][cg * 16 + i * 4 + 2] = v[2];
    tile[r][cg * 16 + i * 4 + 3] = v[3];
  }
  __syncthreads();
  int r2 = tid >> 2, kg = tid & 3;
  u16x8 o0, o1;
  #pragma unroll
  for (int j = 0; j < 8; ++j) o0[j] = f2bf(tile[kg * 16 + j][r2]);
  #pragma unroll
  for (int j = 0; j < 8; ++j) o1[j] = f2bf(tile[kg * 16 + 8 + j][r2]);
  unsigned short* dst = &Wt[(size_t)(a0 + r2) * ENC_D + k0 + kg * 16];
  *reinterpret_cast<u16x8*>(dst) = o0;
  *reinterpret_cast<u16x8*>(dst + 8) = o1;
}

// ---------------- K0b: f_out[n][c][t] = conv129(ali_prev) + F_b ----------------
__global__ void k_conv(const float* __restrict__ ali, const float* __restrict__ Fw,
                       const float* __restrict__ Fb, float* __restrict__ fout) {
  int b = blockIdx.x;
  int tb = b & 7, nc = b >> 3;
  int c = nc % CONV_C, n = nc / CONV_C;
  __shared__ float sa[384];
  __shared__ float sw[129];
  int tid = threadIdx.x;
  int t0 = tb * 256;
  for (int i = tid; i < 384; i += 256) {
    int t = t0 - 64 + i;
    sa[i] = (t >= 0 && t < T_LEN) ? ali[n * T_LEN + t] : 0.f;
  }
  if (tid < 129) sw[tid] = Fw[c * 129 + tid];
  __syncthreads();
  float acc = Fb[c];
  #pragma unroll 8
  for (int k = 0; k < 129; ++k) acc += sw[k] * sa[tid + k];
  fout[(size_t)(n * CONV_C + c) * T_LEN + t0 + tid] = acc;
}

// ---------------- K0c: dec_ws[n][a] = dec_prev[n]@W_dec[:,a] + b_enc[a] ----------------
__global__ void k_dec(const float* __restrict__ dec_prev, const float* __restrict__ Wd,
                      const float* __restrict__ benc, float* __restrict__ dec_ws) {
  int b = blockIdx.x;
  int n = b >> 1, half = b & 1;
  int a = half * 256 + threadIdx.x;
  __shared__ float sd[1024];
  for (int i = threadIdx.x; i < 1024; i += 256) sd[i] = dec_prev[n * 1024 + i];
  __syncthreads();
  float acc = benc[a];
  #pragma unroll 8
  for (int d = 0; d < 1024; ++d) acc += sd[d] * Wd[(size_t)d * ATT_D + a];
  dec_ws[n * ATT_D + a] = acc;
}

// ---------------- K1: fused score GEMM ----------------
// score[h][n*T+t] = sum_{a in half h} w[a]*tanh(enc@W_enc + dec + att)
__global__ __launch_bounds__(256, 3) void k_score(
    const float* __restrict__ enc, const unsigned short* __restrict__ Wt,
    const float* __restrict__ fout, const float* __restrict__ dec_ws,
    const float* __restrict__ W_att, const float* __restrict__ w_vec,
    float* __restrict__ score_ws) {
  __shared__ __align__(16) char smem[51200];

  int bid = blockIdx.x;
  int xcd = bid & 7, idx = bid >> 3;           // nwg=2048, bijective XCD chunking
  int mt = xcd * 128 + (idx >> 1);
  int h = idx & 1;

  int tid = threadIdx.x;
  int w = tid >> 6, lane = tid & 63;
  int l15 = lane & 15, q = lane >> 4;

  const float* Ab = enc + (size_t)mt * (64 * ENC_D);
  const unsigned short* Bb = Wt + (size_t)h * (256 * ENC_D);

  int ra = tid >> 2, ck = (tid & 3) * 8;

  f32x4 acc[4][4];
  #pragma unroll
  for (int m = 0; m < 4; ++m)
    #pragma unroll
    for (int nf = 0; nf < 4; ++nf)
      acc[m][nf] = (f32x4){0.f, 0.f, 0.f, 0.f};

  f32x4 avA0, avA1;
  u16x8 avB[4];

  auto loadG = [&](int kt) {
    const float* p = Ab + (size_t)ra * ENC_D + kt * 32 + ck;
    avA0 = *reinterpret_cast<const f32x4*>(p);
    avA1 = *reinterpret_cast<const f32x4*>(p + 4);
    #pragma unroll
    for (int i = 0; i < 4; ++i) {
      const unsigned short* pb = Bb + (size_t)(ra + i * 64) * ENC_D + kt * 32 + ck;
      avB[i] = *reinterpret_cast<const u16x8*>(pb);
    }
  };
  auto writeL = [&](short* A, short* B) {
    u16x8 t;
    #pragma unroll
    for (int j = 0; j < 4; ++j) t[j] = f2bf(avA0[j]);
    #pragma unroll
    for (int j = 0; j < 4; ++j) t[4 + j] = f2bf(avA1[j]);
    *reinterpret_cast<u16x8*>(&A[ra * 40 + ck]) = t;
    #pragma unroll
    for (int i = 0; i < 4; ++i)
      *reinterpret_cast<u16x8*>(&B[(ra + i * 64) * 40 + ck]) = avB[i];
  };
  auto compute = [&](const short* A, const short* B) {
    s16x8 af[4], bf[4];
    #pragma unroll
    for (int m = 0; m < 4; ++m)
      af[m] = *reinterpret_cast<const s16x8*>(&A[(m * 16 + l15) * 40 + q * 8]);
    #pragma unroll
    for (int nf = 0; nf < 4; ++nf)
      bf[nf] = *reinterpret_cast<const s16x8*>(&B[(w * 64 + nf * 16 + l15) * 40 + q * 8]);
    #pragma unroll
    for (int m = 0; m < 4; ++m)
      #pragma unroll
      for (int nf = 0; nf < 4; ++nf)
        acc[m][nf] = __builtin_amdgcn_mfma_f32_16x16x32_bf16(af[m], bf[nf], acc[m][nf], 0, 0, 0);
  };

  short* A0 = (short*)(smem);
  short* A1 = (short*)(smem + 5120);
  short* B0 = (short*)(smem + 10240);
  short* B1 = (short*)(smem + 30720);

  loadG(0);
  writeL(A0, B0);
  __syncthreads();

  for (int kt = 0; kt < 32; kt += 2) {
    loadG(kt + 1);
    compute(A0, B0);
    __syncthreads();
    writeL(A1, B1);
    __syncthreads();
    if (kt + 2 < 32) loadG(kt + 2);
    compute(A1, B1);
    __syncthreads();
    if (kt + 2 < 32) writeL(A0, B0);
    __syncthreads();
  }

  // ---- epilogue: att mix + dec + tanh + dot(w) + row-reduce ----
  float* f_lds = (float*)smem;               // [10][64]
  float* attw  = (float*)(smem + 2560);      // [256][10]
  float* d_lds = (float*)(smem + 12800);     // [256]
  float* w_lds = (float*)(smem + 13824);     // [256]
  float* red   = (float*)(smem + 14848);     // [4][64]

  int n = mt >> 5;
  int t0 = (mt & 31) * 64;

  for (int i = tid; i < 640; i += 256) {
    int c = i >> 6, tt = i & 63;
    f_lds[c * 64 + tt] = fout[(size_t)(n * CONV_C + c) * T_LEN + t0 + tt];
  }
  for (int i = tid; i < 2560; i += 256) attw[i] = W_att[h * 2560 + i];
  d_lds[tid] = dec_ws[n * ATT_D + h * 256 + tid];
  w_lds[tid] = w_vec[h * 256 + tid];
  __syncthreads();

  float rsum[4][4];
  #pragma unroll
  for (int m = 0; m < 4; ++m) {
    #pragma unroll
    for (int j = 0; j < 4; ++j) {
      int tt = m * 16 + q * 4 + j;
      float s = 0.f;
      #pragma unroll
      for (int nf = 0; nf < 4; ++nf) {
        int cl = w * 64 + nf * 16 + l15;
        float att = 0.f;
        #pragma unroll
        for (int c = 0; c < CONV_C; ++c) att += f_lds[c * 64 + tt] * attw[cl * CONV_C + c];
        float x = acc[m][nf][j] + d_lds[cl] + att;
        float e = __expf(2.f * x);
        float th = 1.f - 2.f / (e + 1.f);
        s += w_lds[cl] * th;
      }
      rsum[m][j] = s;
    }
  }
  #pragma unroll
  for (int m = 0; m < 4; ++m) {
    #pragma unroll
    for (int j = 0; j < 4; ++j) {
      float v = rsum[m][j];
      v += __shfl_xor(v, 1);
      v += __shfl_xor(v, 2);
      v += __shfl_xor(v, 4);
      v += __shfl_xor(v, 8);
      rsum[m][j] = v;
    }
  }
  if (l15 == 0) {
    #pragma unroll
    for (int m = 0; m < 4; ++m)
      #pragma unroll
      for (int j = 0; j < 4; ++j)
        red[w * 64 + m * 16 + q * 4 + j] = rsum[m][j];
  }
  __syncthreads();
  if (tid < 64) {
    float s = red[tid] + red[64 + tid] + red[128 + tid] + red[192 + tid];
    score_ws[(size_t)h * 65536 + (size_t)mt * 64 + tid] = s;
  }
}

// ---------------- K2: masked softmax over T per row ----------------
__global__ void k_softmax(const float* __restrict__ score_ws, const int* __restrict__ enc_len,
                          float* __restrict__ ali_out) {
  __shared__ float wmx[4], wsum[4];
  int n = blockIdx.x, tid = threadIdx.x;
  int len = enc_len[n];
  int w = tid >> 6, lane = tid & 63;
  float s[8], e[8];
  float mx = -1e30f;
  #pragma unroll
  for (int i = 0; i < 8; ++i) {
    int t = i * 256 + tid;
    float v = score_ws[n * T_LEN + t] + score_ws[65536 + n * T_LEN + t];
    s[i] = v;
    if (t < len) mx = fmaxf(mx, v);
  }
  #pragma unroll
  for (int off = 32; off; off >>= 1) mx = fmaxf(mx, __shfl_xor(mx, off));
  if (lane == 0) wmx[w] = mx;
  __syncthreads();
  mx = fmaxf(fmaxf(wmx[0], wmx[1]), fmaxf(wmx[2], wmx[3]));
  float sum = 0.f;
  #pragma unroll
  for (int i = 0; i < 8; ++i) {
    int t = i * 256 + tid;
    float v = (t < len) ? __expf(s[i] - mx) : 0.f;
    e[i] = v;
    sum += v;
  }
  #pragma unroll
  for (int off = 32; off; off >>= 1) sum += __shfl_xor(sum, off);
  if (lane == 0) wsum[w] = sum;
  __syncthreads();
  sum = wsum[0] + wsum[1] + wsum[2] + wsum[3];
  float inv = 1.f / sum;
  #pragma unroll
  for (int i = 0; i < 8; ++i) ali_out[n * T_LEN + i * 256 + tid] = e[i] * inv;
}

// ---------------- K3: ctx partials over T-chunks ----------------
__global__ void k_ctx(const float* __restrict__ ali, const float* __restrict__ enc,
                      float* __restrict__ part) {
  int b = blockIdx.x;                   // n*32 + tc
  int n = b >> 5, tc = b & 31;
  int tid = threadIdx.x;
  f32x4 acc = (f32x4){0.f, 0.f, 0.f, 0.f};
  const float* ep = enc + (size_t)(n * T_LEN + tc * 64) * ENC_D + tid * 4;
  const float* ap = ali + n * T_LEN + tc * 64;
  #pragma unroll 4
  for (int i = 0; i < 64; ++i) {
    float a = ap[i];
    f32x4 ev = *reinterpret_cast<const f32x4*>(ep + (size_t)i * ENC_D);
    acc += ev * a;
  }
  *reinterpret_cast<f32x4*>(&part[(size_t)b * ENC_D + tid * 4]) = acc;
}

// ---------------- K4: reduce ctx partials ----------------
__global__ void k_ctx_red(const float* __restrict__ part, float* __restrict__ ctx_out) {
  int g = blockIdx.x * 256 + threadIdx.x;
  int n = g >> 10, d = g & 1023;
  float s = 0.f;
  #pragma unroll 8
  for (int tc = 0; tc < 32; ++tc) s += part[(size_t)(n * 32 + tc) * ENC_D + d];
  ctx_out[g] = s;
}

extern "C" void kernel_launch(void* const* d_in, const int* in_sizes, int n_in,
                              void* d_out, int out_size, void* d_ws, size_t ws_size,
                              hipStream_t stream) {
  const float* enc      = (const float*)d_in[0];
  const int*   enc_len  = (const int*)d_in[1];
  const float* dec_prev = (const float*)d_in[2];
  const float* ali_prev = (const float*)d_in[3];
  const float* W_enc    = (const float*)d_in[4];
  const float* b_enc    = (const float*)d_in[5];
  const float* W_dec    = (const float*)d_in[6];
  const float* F_w      = (const float*)d_in[7];
  const float* F_b      = (const float*)d_in[8];
  const float* W_att    = (const float*)d_in[9];
  const float* w_vec    = (const float*)d_in[10];
  float* out = (float*)d_out;

  char* ws = (char*)d_ws;
  unsigned short* Wt = (unsigned short*)ws;        // 1,048,576 B
  float* fout   = (float*)(ws + 1048576);          // 2,621,440 B
  float* dec_ws = (float*)(ws + 3670016);          //    65,536 B
  float* score  = (float*)(ws + 3735552);          //   524,288 B
  float* part   = (float*)(ws + 4259840);          // 4,194,304 B

  dim3 blk(256);
  hipLaunchKernelGGL(k_wt, dim3(16, 8), blk, 0, stream, W_enc, Wt);
  hipLaunchKernelGGL(k_conv, dim3(2560), blk, 0, stream, ali_prev, F_w, F_b, fout);
  hipLaunchKernelGGL(k_dec, dim3(64), blk, 0, stream, dec_prev, W_dec, b_enc, dec_ws);
  hipLaunchKernelGGL(k_score, dim3(2048), blk, 0, stream, enc, Wt, fout, dec_ws, W_att, w_vec, score);
  hipLaunchKernelGGL(k_softmax, dim3(32), blk, 0, stream, score, enc_len, out);
  hipLaunchKernelGGL(k_ctx, dim3(1024), blk, 0, stream, out, enc, part);
  hipLaunchKernelGGL(k_ctx_red, dim3(128), blk, 0, stream, part, out + 65536);
}